// Round 4
// baseline (5982.559 us; speedup 1.0000x reference)
//
#include <hip/hip_runtime.h>
#include <math.h>

// Sizes fixed by the problem
#define BATCH 128
#define TT 512      // time steps
#define CIN 512
#define HID 256
#define GG 1024     // 4*HID

typedef _Float16 half2_t __attribute__((ext_vector_type(2)));

__device__ __forceinline__ float sigf(float x) { return 1.f / (1.f + __expf(-x)); }
__device__ __forceinline__ float tanhf_(float x) {
    float a = fabsf(x);
    float e = __expf(-2.f * a);
    float r = (1.f - e) / (1.f + e);
    return copysignf(r, x);
}

// v_dot2_f32_f16: 2-way f16 dot with fp32 accumulate
__device__ __forceinline__ float fdot2_(half2_t a, half2_t b, float c) {
#if __has_builtin(__builtin_amdgcn_fdot2)
    return __builtin_amdgcn_fdot2(a, b, c, false);
#else
    return c + (float)a.x * (float)b.x + (float)a.y * (float)b.y;
#endif
}

// C[b][m,n] = relu( sum_k W[m,k] * X[b][k,n] + bias[m] )
__global__ __launch_bounds__(256) void wgemm_bias_relu(
    const float* __restrict__ W, const float* __restrict__ X,
    const float* __restrict__ bias, float* __restrict__ Y,
    int M, int N, int K)
{
    const int b = blockIdx.z;
    const float* Xb = X + (size_t)b * K * N;
    float* Yb = Y + (size_t)b * M * N;
    const int m0 = blockIdx.y * 64, n0 = blockIdx.x * 64;
    __shared__ float As[16][68];
    __shared__ float Bs[16][64];
    const int tid = threadIdx.x;
    const int tx = tid & 15, ty = tid >> 4;
    float acc[4][4] = {{0.f, 0.f, 0.f, 0.f}, {0.f, 0.f, 0.f, 0.f},
                       {0.f, 0.f, 0.f, 0.f}, {0.f, 0.f, 0.f, 0.f}};
    for (int k0 = 0; k0 < K; k0 += 16) {
        {
            const int m = tid >> 2, kq = (tid & 3) << 2;
            float4 a = *(const float4*)(W + (size_t)(m0 + m) * K + k0 + kq);
            As[kq + 0][m] = a.x; As[kq + 1][m] = a.y;
            As[kq + 2][m] = a.z; As[kq + 3][m] = a.w;
            const int kk = tid >> 4, n4 = (tid & 15) << 2;
            float4 xv = *(const float4*)(Xb + (size_t)(k0 + kk) * N + n0 + n4);
            *(float4*)&Bs[kk][n4] = xv;
        }
        __syncthreads();
        #pragma unroll
        for (int k = 0; k < 16; ++k) {
            const float4 a = *(const float4*)&As[k][ty << 2];
            const float4 b4 = *(const float4*)&Bs[k][tx << 2];
            const float av[4] = {a.x, a.y, a.z, a.w};
            const float bv[4] = {b4.x, b4.y, b4.z, b4.w};
            #pragma unroll
            for (int i = 0; i < 4; ++i)
                #pragma unroll
                for (int j = 0; j < 4; ++j)
                    acc[i][j] += av[i] * bv[j];
        }
        __syncthreads();
    }
    #pragma unroll
    for (int i = 0; i < 4; ++i) {
        const int m = m0 + (ty << 2) + i;
        const float bi = bias[m];
        float4 r;
        r.x = fmaxf(acc[i][0] + bi, 0.f);
        r.y = fmaxf(acc[i][1] + bi, 0.f);
        r.z = fmaxf(acc[i][2] + bi, 0.f);
        r.w = fmaxf(acc[i][3] + bi, 0.f);
        *(float4*)(Yb + (size_t)m * N + n0 + (tx << 2)) = r;
    }
}

// C[r,n] = sum_k A[r,k]*Bt[n,k] + bias1[n] + bias2[n]
__global__ __launch_bounds__(256) void gemm_abt_bias(
    const float* __restrict__ A, const float* __restrict__ Bt,
    const float* __restrict__ bias1, const float* __restrict__ bias2,
    float* __restrict__ C, int M, int N, int K)
{
    const int r0 = blockIdx.y * 64, n0 = blockIdx.x * 64;
    __shared__ float As[16][68];
    __shared__ float Bs[16][68];
    const int tid = threadIdx.x;
    const int tx = tid & 15, ty = tid >> 4;
    float acc[4][4] = {{0.f, 0.f, 0.f, 0.f}, {0.f, 0.f, 0.f, 0.f},
                       {0.f, 0.f, 0.f, 0.f}, {0.f, 0.f, 0.f, 0.f}};
    for (int k0 = 0; k0 < K; k0 += 16) {
        {
            const int r = tid >> 2, kq = (tid & 3) << 2;
            float4 a = *(const float4*)(A + (size_t)(r0 + r) * K + k0 + kq);
            As[kq + 0][r] = a.x; As[kq + 1][r] = a.y;
            As[kq + 2][r] = a.z; As[kq + 3][r] = a.w;
            float4 bq = *(const float4*)(Bt + (size_t)(n0 + r) * K + k0 + kq);
            Bs[kq + 0][r] = bq.x; Bs[kq + 1][r] = bq.y;
            Bs[kq + 2][r] = bq.z; Bs[kq + 3][r] = bq.w;
        }
        __syncthreads();
        #pragma unroll
        for (int k = 0; k < 16; ++k) {
            const float4 a = *(const float4*)&As[k][ty << 2];
            const float4 b4 = *(const float4*)&Bs[k][tx << 2];
            const float av[4] = {a.x, a.y, a.z, a.w};
            const float bv[4] = {b4.x, b4.y, b4.z, b4.w};
            #pragma unroll
            for (int i = 0; i < 4; ++i)
                #pragma unroll
                for (int j = 0; j < 4; ++j)
                    acc[i][j] += av[i] * bv[j];
        }
        __syncthreads();
    }
    float bb[4];
    #pragma unroll
    for (int j = 0; j < 4; ++j) {
        const int n = n0 + (tx << 2) + j;
        bb[j] = bias1[n] + bias2[n];
    }
    #pragma unroll
    for (int i = 0; i < 4; ++i) {
        const int r = r0 + (ty << 2) + i;
        float4 v;
        v.x = acc[i][0] + bb[0];
        v.y = acc[i][1] + bb[1];
        v.z = acc[i][2] + bb[2];
        v.w = acc[i][3] + bb[3];
        *(float4*)(C + (size_t)r * N + n0 + (tx << 2)) = v;
    }
}

// Forward LSTM scan v3: 2 blocks/batch, register-resident f16 weights,
// wave-uniform (broadcast) LDS h-reads, single-wave finisher.
//   block bid < 128:  batch bid,      units [0,128)   ("lo")
//   block bid >= 128: batch bid-128,  units [128,256) ("hi")
// Thread map: rw = tid&511 (local gate row: q=rw>>7, u=rw&127),
//             half = tid>>9 (K-half). Waves 0-7 are half 0, waves 8-15 half 1
//             -> all 64 lanes of a wave read the SAME hsh address
//             -> pure LDS broadcast, zero bank conflicts (round-3 fix).
// K-half partials combine through psh[1024]; wave 0 (lane l = units 2l,2l+1)
// does the nonlinearity, h-store, and the inter-block exchange. Store->flag
// ordering inside wave 0 via s_waitcnt vmcnt(0); 2 barriers/step (was 3).
__global__ __launch_bounds__(1024, 4) void lstm_scan3(
    const float* __restrict__ xg, const float* __restrict__ whh,
    float* __restrict__ out, unsigned int* __restrict__ xb,
    int* __restrict__ flags)
{
    const int tid = threadIdx.x;
    const int bid = blockIdx.x;
    const int is_hi = (bid >= 128) ? 1 : 0;
    const int g = is_hi ? bid - 128 : bid;
    const int partner = is_hi ? bid - 128 : bid + 128;
    const int half = tid >> 9;         // K-half: k in [128*half, 128*half+128)
    const int rw = tid & 511;          // local row 0..511
    const int q = rw >> 7;             // gate 0..3 (i,f,g,o)
    const int u = rw & 127;            // local unit
    const int row = q * 256 + is_hi * 128 + u;   // global gate row

    __shared__ __align__(16) unsigned int hsh[128];  // h: 256 f16 (lo|hi)
    __shared__ float psh[1024];                      // K-half partial sums

    // Weights: 64 half2 VGPRs per thread, statically indexed (must not spill)
    half2_t w[64];
    {
        const float4* wp = (const float4*)(whh + (size_t)row * 256 + half * 128);
        #pragma unroll
        for (int k = 0; k < 32; ++k) {
            float4 a = wp[k];
            w[2 * k + 0] = half2_t{(_Float16)a.x, (_Float16)a.y};
            w[2 * k + 1] = half2_t{(_Float16)a.z, (_Float16)a.w};
        }
    }
    if (tid < 128) hsh[tid] = 0u;
    const float* xgb = xg + (size_t)g * TT * GG;
    float xnext = (half == 0) ? xgb[row] : 0.f;
    float c0 = 0.f, c1 = 0.f, hk0 = 0.f, hk1 = 0.f;  // live in wave 0 lanes
    __syncthreads();

    for (int t = 0; t < TT; ++t) {
        const float xv = xnext;
        if (half == 0 && t < TT - 1) xnext = xgb[(size_t)(t + 1) * GG + row];
        float a0 = 0.f, a1 = 0.f, a2 = 0.f, a3 = 0.f;
        const float4* hp = (const float4*)hsh + (half << 4);
        #pragma unroll 4
        for (int kk = 0; kk < 16; ++kk) {
            const float4 hv = hp[kk];   // wave-uniform address -> broadcast
            a0 = fdot2_(w[4 * kk + 0], __builtin_bit_cast(half2_t, hv.x), a0);
            a1 = fdot2_(w[4 * kk + 1], __builtin_bit_cast(half2_t, hv.y), a1);
            a2 = fdot2_(w[4 * kk + 2], __builtin_bit_cast(half2_t, hv.z), a2);
            a3 = fdot2_(w[4 * kk + 3], __builtin_bit_cast(half2_t, hv.w), a3);
        }
        psh[tid] = (a0 + a1) + (a2 + a3) + xv;
        __syncthreads();               // B1: partials staged; h reads done
        if (tid < 64) {                // wave 0 finishes units 2l, 2l+1
            const int l = tid;
            const float2* pl = (const float2*)psh;          // half-0 rows
            const float2* ph = (const float2*)(psh + 512);  // half-1 rows
            const float2 iv = pl[l],       iw = ph[l];
            const float2 fv = pl[64 + l],  fw = ph[64 + l];
            const float2 gv = pl[128 + l], gw = ph[128 + l];
            const float2 ov = pl[192 + l], ow = ph[192 + l];
            const float i0 = sigf(iv.x + iw.x), i1 = sigf(iv.y + iw.y);
            const float f0 = sigf(fv.x + fw.x), f1 = sigf(fv.y + fw.y);
            const float g0 = tanhf_(gv.x + gw.x), g1 = tanhf_(gv.y + gw.y);
            const float o0 = sigf(ov.x + ow.x), o1 = sigf(ov.y + ow.y);
            c0 = f0 * c0 + i0 * g0;  hk0 = o0 * tanhf_(c0);
            c1 = f1 * c1 + i1 * g1;  hk1 = o1 * tanhf_(c1);
            const unsigned int hv =
                (unsigned int)__builtin_bit_cast(unsigned short, (_Float16)hk0) |
                ((unsigned int)__builtin_bit_cast(unsigned short, (_Float16)hk1) << 16);
            hsh[is_hi * 64 + l] = hv;  // own half into LDS
            if (t < TT - 1) {
                unsigned int* dst =
                    xb + (((size_t)g * 2 + (t & 1)) * 2 + is_hi) * 64;
                __hip_atomic_store(&dst[l], hv, __ATOMIC_RELAXED,
                                   __HIP_MEMORY_SCOPE_AGENT);
                asm volatile("s_waitcnt vmcnt(0)" ::: "memory");
                if (l == 0) {          // flag after stores acked at MALL
                    __hip_atomic_store(&flags[bid * 32], t + 1,
                                       __ATOMIC_RELAXED, __HIP_MEMORY_SCOPE_AGENT);
                    while (__hip_atomic_load(&flags[partner * 32],
                                             __ATOMIC_RELAXED,
                                             __HIP_MEMORY_SCOPE_AGENT) < t + 1)
                        __builtin_amdgcn_s_sleep(1);
                }
                asm volatile("" ::: "memory");  // loads stay after the poll
                const unsigned int* src =
                    xb + (((size_t)g * 2 + (t & 1)) * 2 + (1 - is_hi)) * 64;
                hsh[(1 - is_hi) * 64 + l] =
                    __hip_atomic_load(&src[l], __ATOMIC_RELAXED,
                                      __HIP_MEMORY_SCOPE_AGENT);
            }
        }
        __syncthreads();               // B2: h (own + partner) visible to all
    }
    if (tid < 64) {
        out[(size_t)g * 512 + is_hi * 128 + 2 * tid + 0] = hk0;
        out[(size_t)g * 512 + is_hi * 128 + 2 * tid + 1] = hk1;
    }
}

// Backward-direction LSTM, last output only = FIRST step of the reversed scan
// with h=c=0: gates depend only on seq[:, T-1, :] @ w_ih_b^T + biases.
__global__ __launch_bounds__(256) void lstm_back_last(
    const float* __restrict__ y2, const float* __restrict__ wih,
    const float* __restrict__ bih, const float* __restrict__ bhh,
    float* __restrict__ out)
{
    const int b = blockIdx.x;
    const int t = threadIdx.x;
    __shared__ float s[256];
    s[t] = y2[(size_t)b * (HID * TT) + (TT - 1) * HID + t];
    __syncthreads();
    float acc[4];
    #pragma unroll
    for (int q = 0; q < 4; ++q) acc[q] = bih[t + q * 256] + bhh[t + q * 256];
    #pragma unroll
    for (int q = 0; q < 4; ++q) {
        const float* w = wih + (size_t)(t + q * 256) * 256;
        float a = acc[q];
        for (int k = 0; k < 256; k += 4) {
            const float4 w4 = *(const float4*)&w[k];
            const float4 h4 = *(const float4*)&s[k];
            a += w4.x * h4.x; a += w4.y * h4.y;
            a += w4.z * h4.z; a += w4.w * h4.w;
        }
        acc[q] = a;
    }
    const float i = sigf(acc[0]);
    const float g = tanhf_(acc[2]), o = sigf(acc[3]);
    const float c = i * g;           // c_prev = 0, forget path vanishes
    const float h = o * tanhf_(c);
    out[(size_t)b * 512 + 256 + t] = h;
}

extern "C" void kernel_launch(void* const* d_in, const int* in_sizes, int n_in,
                              void* d_out, int out_size, void* d_ws, size_t ws_size,
                              hipStream_t stream) {
    const float* x      = (const float*)d_in[0];
    const float* w1     = (const float*)d_in[1];
    const float* b1     = (const float*)d_in[2];
    const float* w2     = (const float*)d_in[3];
    const float* b2     = (const float*)d_in[4];
    const float* w_ih_f = (const float*)d_in[5];
    const float* w_hh_f = (const float*)d_in[6];
    const float* b_ih_f = (const float*)d_in[7];
    const float* b_hh_f = (const float*)d_in[8];
    const float* w_ih_b = (const float*)d_in[9];
    // d_in[10] = w_hh_b: provably unused (only first reversed step reaches the output)
    const float* b_ih_b = (const float*)d_in[11];
    const float* b_hh_b = (const float*)d_in[12];
    float* out = (float*)d_out;

    // Workspace layout (floats):
    //   y2 : [0, 16777216)                 67.1 MB  (= seq; dead once back_last ran)
    //   y1 : [16777216, 33554432)          67.1 MB  (dead after conv2)
    //   xg : [16777216, 83886080)         268.4 MB  (overlays y1)
    //   flags: y2[0:8192)      32 KB  (padded: 1 flag per 128 B)  } overlay y2,
    //   xbuf : y2[8192:40960) 128 KB  (h-exchange, 2 slots/dir)   } after back_last
    float* ws = (float*)d_ws;
    float* y2 = ws;
    float* y1 = ws + (size_t)16777216;
    float* xg = ws + (size_t)16777216;
    int* flags = (int*)ws;
    unsigned int* xb = (unsigned int*)ws + 8192;

    // conv1: M=256, N=512, K=512
    wgemm_bias_relu<<<dim3(8, 4, BATCH), 256, 0, stream>>>(w1, x, b1, y1, HID, TT, CIN);
    // conv2: M=256, N=512, K=256
    wgemm_bias_relu<<<dim3(8, 4, BATCH), 256, 0, stream>>>(w2, y1, b2, y2, HID, TT, HID);
    // xg_f = seq @ w_ih_f^T + b_ih_f + b_hh_f : M=65536, N=1024, K=256
    gemm_abt_bias<<<dim3(16, 1024), 256, 0, stream>>>(y2, w_ih_f, b_ih_f, b_hh_f,
                                                      xg, BATCH * TT, GG, HID);
    // backward last step first (frees y2 region for the exchange buffers)
    lstm_back_last<<<BATCH, 256, 0, stream>>>(y2, w_ih_b, b_ih_b, b_hh_b, out);
    // zero the handshake flags (harness poisons ws each call)
    hipMemsetAsync(flags, 0, 32768, stream);
    // forward scan (writes out[:, 0:256))
    lstm_scan3<<<256, 1024, 0, stream>>>(xg, w_hh_f, out, xb, flags);
}

// Round 5
// 2145.429 us; speedup vs baseline: 2.7885x; 2.7885x over previous
//
#include <hip/hip_runtime.h>
#include <math.h>

// Sizes fixed by the problem
#define BATCH 128
#define TT 512      // time steps
#define CIN 512
#define HID 256
#define GG 1024     // 4*HID

typedef _Float16 half2_t __attribute__((ext_vector_type(2)));

__device__ __forceinline__ float sigf(float x) { return 1.f / (1.f + __expf(-x)); }
__device__ __forceinline__ float tanhf_(float x) {
    float a = fabsf(x);
    float e = __expf(-2.f * a);
    float r = (1.f - e) / (1.f + e);
    return copysignf(r, x);
}

// v_dot2_f32_f16: 2-way f16 dot with fp32 accumulate
__device__ __forceinline__ float fdot2_(half2_t a, half2_t b, float c) {
#if __has_builtin(__builtin_amdgcn_fdot2)
    return __builtin_amdgcn_fdot2(a, b, c, false);
#else
    return c + (float)a.x * (float)b.x + (float)a.y * (float)b.y;
#endif
}

// C[b][m,n] = relu( sum_k W[m,k] * X[b][k,n] + bias[m] )
__global__ __launch_bounds__(256) void wgemm_bias_relu(
    const float* __restrict__ W, const float* __restrict__ X,
    const float* __restrict__ bias, float* __restrict__ Y,
    int M, int N, int K)
{
    const int b = blockIdx.z;
    const float* Xb = X + (size_t)b * K * N;
    float* Yb = Y + (size_t)b * M * N;
    const int m0 = blockIdx.y * 64, n0 = blockIdx.x * 64;
    __shared__ float As[16][68];
    __shared__ float Bs[16][64];
    const int tid = threadIdx.x;
    const int tx = tid & 15, ty = tid >> 4;
    float acc[4][4] = {{0.f, 0.f, 0.f, 0.f}, {0.f, 0.f, 0.f, 0.f},
                       {0.f, 0.f, 0.f, 0.f}, {0.f, 0.f, 0.f, 0.f}};
    for (int k0 = 0; k0 < K; k0 += 16) {
        {
            const int m = tid >> 2, kq = (tid & 3) << 2;
            float4 a = *(const float4*)(W + (size_t)(m0 + m) * K + k0 + kq);
            As[kq + 0][m] = a.x; As[kq + 1][m] = a.y;
            As[kq + 2][m] = a.z; As[kq + 3][m] = a.w;
            const int kk = tid >> 4, n4 = (tid & 15) << 2;
            float4 xv = *(const float4*)(Xb + (size_t)(k0 + kk) * N + n0 + n4);
            *(float4*)&Bs[kk][n4] = xv;
        }
        __syncthreads();
        #pragma unroll
        for (int k = 0; k < 16; ++k) {
            const float4 a = *(const float4*)&As[k][ty << 2];
            const float4 b4 = *(const float4*)&Bs[k][tx << 2];
            const float av[4] = {a.x, a.y, a.z, a.w};
            const float bv[4] = {b4.x, b4.y, b4.z, b4.w};
            #pragma unroll
            for (int i = 0; i < 4; ++i)
                #pragma unroll
                for (int j = 0; j < 4; ++j)
                    acc[i][j] += av[i] * bv[j];
        }
        __syncthreads();
    }
    #pragma unroll
    for (int i = 0; i < 4; ++i) {
        const int m = m0 + (ty << 2) + i;
        const float bi = bias[m];
        float4 r;
        r.x = fmaxf(acc[i][0] + bi, 0.f);
        r.y = fmaxf(acc[i][1] + bi, 0.f);
        r.z = fmaxf(acc[i][2] + bi, 0.f);
        r.w = fmaxf(acc[i][3] + bi, 0.f);
        *(float4*)(Yb + (size_t)m * N + n0 + (tx << 2)) = r;
    }
}

// C[r,n] = sum_k A[r,k]*Bt[n,k] + bias1[n] + bias2[n]
__global__ __launch_bounds__(256) void gemm_abt_bias(
    const float* __restrict__ A, const float* __restrict__ Bt,
    const float* __restrict__ bias1, const float* __restrict__ bias2,
    float* __restrict__ C, int M, int N, int K)
{
    const int r0 = blockIdx.y * 64, n0 = blockIdx.x * 64;
    __shared__ float As[16][68];
    __shared__ float Bs[16][68];
    const int tid = threadIdx.x;
    const int tx = tid & 15, ty = tid >> 4;
    float acc[4][4] = {{0.f, 0.f, 0.f, 0.f}, {0.f, 0.f, 0.f, 0.f},
                       {0.f, 0.f, 0.f, 0.f}, {0.f, 0.f, 0.f, 0.f}};
    for (int k0 = 0; k0 < K; k0 += 16) {
        {
            const int r = tid >> 2, kq = (tid & 3) << 2;
            float4 a = *(const float4*)(A + (size_t)(r0 + r) * K + k0 + kq);
            As[kq + 0][r] = a.x; As[kq + 1][r] = a.y;
            As[kq + 2][r] = a.z; As[kq + 3][r] = a.w;
            float4 bq = *(const float4*)(Bt + (size_t)(n0 + r) * K + k0 + kq);
            Bs[kq + 0][r] = bq.x; Bs[kq + 1][r] = bq.y;
            Bs[kq + 2][r] = bq.z; Bs[kq + 3][r] = bq.w;
        }
        __syncthreads();
        #pragma unroll
        for (int k = 0; k < 16; ++k) {
            const float4 a = *(const float4*)&As[k][ty << 2];
            const float4 b4 = *(const float4*)&Bs[k][tx << 2];
            const float av[4] = {a.x, a.y, a.z, a.w};
            const float bv[4] = {b4.x, b4.y, b4.z, b4.w};
            #pragma unroll
            for (int i = 0; i < 4; ++i)
                #pragma unroll
                for (int j = 0; j < 4; ++j)
                    acc[i][j] += av[i] * bv[j];
        }
        __syncthreads();
    }
    float bb[4];
    #pragma unroll
    for (int j = 0; j < 4; ++j) {
        const int n = n0 + (tx << 2) + j;
        bb[j] = bias1[n] + bias2[n];
    }
    #pragma unroll
    for (int i = 0; i < 4; ++i) {
        const int r = r0 + (ty << 2) + i;
        float4 v;
        v.x = acc[i][0] + bb[0];
        v.y = acc[i][1] + bb[1];
        v.z = acc[i][2] + bb[2];
        v.w = acc[i][3] + bb[3];
        *(float4*)(C + (size_t)r * N + n0 + (tx << 2)) = v;
    }
}

// Forward LSTM scan v4 = v3 structure with the dot loop FULLY unrolled.
// (Round-4 lesson: "#pragma unroll 4" leaves kk dynamic -> w[] dynamically
// indexed -> compiler demotes weights to scratch -> 16.8 GB/dispatch re-fetch.
// Full unroll keeps all w[] indices static -> register-resident, FETCH ~170MB.)
//   block bid < 128:  batch bid,      units [0,128)   ("lo")
//   block bid >= 128: batch bid-128,  units [128,256) ("hi")
// Thread map: rw = tid&511 (q=rw>>7 gate, u=rw&127 unit), half = tid>>9.
// Waves 0-7 = K-half 0, waves 8-15 = K-half 1 -> dot-loop LDS reads are
// wave-uniform -> pure broadcast, zero bank conflicts (verified round 4).
// K-half partials combine via psh[1024]; wave 0 (lane l = units 2l,2l+1)
// runs the nonlinearity + inter-block h exchange (relaxed agent-scope
// atomics through MALL, store->flag ordered by in-wave s_waitcnt vmcnt(0)).
__global__ __launch_bounds__(1024, 4) void lstm_scan4(
    const float* __restrict__ xg, const float* __restrict__ whh,
    float* __restrict__ out, unsigned int* __restrict__ xb,
    int* __restrict__ flags)
{
    const int tid = threadIdx.x;
    const int bid = blockIdx.x;
    const int is_hi = (bid >= 128) ? 1 : 0;
    const int g = is_hi ? bid - 128 : bid;
    const int partner = is_hi ? bid - 128 : bid + 128;
    const int half = tid >> 9;         // K-half: k in [128*half, 128*half+128)
    const int rw = tid & 511;          // local row 0..511
    const int q = rw >> 7;             // gate 0..3 (i,f,g,o)
    const int u = rw & 127;            // local unit
    const int row = q * 256 + is_hi * 128 + u;   // global gate row

    __shared__ __align__(16) unsigned int hsh[128];  // h: 256 f16 (lo|hi)
    __shared__ float psh[1024];                      // K-half partial sums

    // Weights: 64 half2 VGPRs per thread, statically indexed (must not spill)
    half2_t w[64];
    {
        const float4* wp = (const float4*)(whh + (size_t)row * 256 + half * 128);
        #pragma unroll
        for (int k = 0; k < 32; ++k) {
            float4 a = wp[k];
            w[2 * k + 0] = half2_t{(_Float16)a.x, (_Float16)a.y};
            w[2 * k + 1] = half2_t{(_Float16)a.z, (_Float16)a.w};
        }
    }
    if (tid < 128) hsh[tid] = 0u;
    const float* xgb = xg + (size_t)g * TT * GG;
    float xnext = (half == 0) ? xgb[row] : 0.f;
    float c0 = 0.f, c1 = 0.f, hk0 = 0.f, hk1 = 0.f;  // live in wave 0 lanes
    __syncthreads();

    for (int t = 0; t < TT; ++t) {
        const float xv = xnext;
        if (half == 0 && t < TT - 1) xnext = xgb[(size_t)(t + 1) * GG + row];
        float a0 = 0.f, a1 = 0.f, a2 = 0.f, a3 = 0.f;
        const float4* hp = (const float4*)hsh + (half << 4);
        #pragma unroll
        for (int kk = 0; kk < 16; ++kk) {
            const float4 hv = hp[kk];   // wave-uniform address -> broadcast
            a0 = fdot2_(w[4 * kk + 0], __builtin_bit_cast(half2_t, hv.x), a0);
            a1 = fdot2_(w[4 * kk + 1], __builtin_bit_cast(half2_t, hv.y), a1);
            a2 = fdot2_(w[4 * kk + 2], __builtin_bit_cast(half2_t, hv.z), a2);
            a3 = fdot2_(w[4 * kk + 3], __builtin_bit_cast(half2_t, hv.w), a3);
        }
        psh[tid] = (a0 + a1) + (a2 + a3) + xv;
        __syncthreads();               // B1: partials staged; h reads done
        if (tid < 64) {                // wave 0 finishes units 2l, 2l+1
            const int l = tid;
            const float2* pl = (const float2*)psh;          // half-0 rows
            const float2* ph = (const float2*)(psh + 512);  // half-1 rows
            const float2 iv = pl[l],       iw = ph[l];
            const float2 fv = pl[64 + l],  fw = ph[64 + l];
            const float2 gv = pl[128 + l], gw = ph[128 + l];
            const float2 ov = pl[192 + l], ow = ph[192 + l];
            const float i0 = sigf(iv.x + iw.x), i1 = sigf(iv.y + iw.y);
            const float f0 = sigf(fv.x + fw.x), f1 = sigf(fv.y + fw.y);
            const float g0 = tanhf_(gv.x + gw.x), g1 = tanhf_(gv.y + gw.y);
            const float o0 = sigf(ov.x + ow.x), o1 = sigf(ov.y + ow.y);
            c0 = f0 * c0 + i0 * g0;  hk0 = o0 * tanhf_(c0);
            c1 = f1 * c1 + i1 * g1;  hk1 = o1 * tanhf_(c1);
            const unsigned int hv =
                (unsigned int)__builtin_bit_cast(unsigned short, (_Float16)hk0) |
                ((unsigned int)__builtin_bit_cast(unsigned short, (_Float16)hk1) << 16);
            hsh[is_hi * 64 + l] = hv;  // own half into LDS
            if (t < TT - 1) {
                unsigned int* dst =
                    xb + (((size_t)g * 2 + (t & 1)) * 2 + is_hi) * 64;
                __hip_atomic_store(&dst[l], hv, __ATOMIC_RELAXED,
                                   __HIP_MEMORY_SCOPE_AGENT);
                asm volatile("s_waitcnt vmcnt(0)" ::: "memory");
                if (l == 0) {          // flag after stores acked at MALL
                    __hip_atomic_store(&flags[bid * 32], t + 1,
                                       __ATOMIC_RELAXED, __HIP_MEMORY_SCOPE_AGENT);
                    while (__hip_atomic_load(&flags[partner * 32],
                                             __ATOMIC_RELAXED,
                                             __HIP_MEMORY_SCOPE_AGENT) < t + 1)
                        __builtin_amdgcn_s_sleep(1);
                }
                asm volatile("" ::: "memory");  // loads stay after the poll
                const unsigned int* src =
                    xb + (((size_t)g * 2 + (t & 1)) * 2 + (1 - is_hi)) * 64;
                hsh[(1 - is_hi) * 64 + l] =
                    __hip_atomic_load(&src[l], __ATOMIC_RELAXED,
                                      __HIP_MEMORY_SCOPE_AGENT);
            }
        }
        __syncthreads();               // B2: h (own + partner) visible to all
    }
    if (tid < 64) {
        out[(size_t)g * 512 + is_hi * 128 + 2 * tid + 0] = hk0;
        out[(size_t)g * 512 + is_hi * 128 + 2 * tid + 1] = hk1;
    }
}

// Backward-direction LSTM, last output only = FIRST step of the reversed scan
// with h=c=0: gates depend only on seq[:, T-1, :] @ w_ih_b^T + biases.
__global__ __launch_bounds__(256) void lstm_back_last(
    const float* __restrict__ y2, const float* __restrict__ wih,
    const float* __restrict__ bih, const float* __restrict__ bhh,
    float* __restrict__ out)
{
    const int b = blockIdx.x;
    const int t = threadIdx.x;
    __shared__ float s[256];
    s[t] = y2[(size_t)b * (HID * TT) + (TT - 1) * HID + t];
    __syncthreads();
    float acc[4];
    #pragma unroll
    for (int q = 0; q < 4; ++q) acc[q] = bih[t + q * 256] + bhh[t + q * 256];
    #pragma unroll
    for (int q = 0; q < 4; ++q) {
        const float* w = wih + (size_t)(t + q * 256) * 256;
        float a = acc[q];
        for (int k = 0; k < 256; k += 4) {
            const float4 w4 = *(const float4*)&w[k];
            const float4 h4 = *(const float4*)&s[k];
            a += w4.x * h4.x; a += w4.y * h4.y;
            a += w4.z * h4.z; a += w4.w * h4.w;
        }
        acc[q] = a;
    }
    const float i = sigf(acc[0]);
    const float g = tanhf_(acc[2]), o = sigf(acc[3]);
    const float c = i * g;           // c_prev = 0, forget path vanishes
    const float h = o * tanhf_(c);
    out[(size_t)b * 512 + 256 + t] = h;
}

extern "C" void kernel_launch(void* const* d_in, const int* in_sizes, int n_in,
                              void* d_out, int out_size, void* d_ws, size_t ws_size,
                              hipStream_t stream) {
    const float* x      = (const float*)d_in[0];
    const float* w1     = (const float*)d_in[1];
    const float* b1     = (const float*)d_in[2];
    const float* w2     = (const float*)d_in[3];
    const float* b2     = (const float*)d_in[4];
    const float* w_ih_f = (const float*)d_in[5];
    const float* w_hh_f = (const float*)d_in[6];
    const float* b_ih_f = (const float*)d_in[7];
    const float* b_hh_f = (const float*)d_in[8];
    const float* w_ih_b = (const float*)d_in[9];
    // d_in[10] = w_hh_b: provably unused (only first reversed step reaches the output)
    const float* b_ih_b = (const float*)d_in[11];
    const float* b_hh_b = (const float*)d_in[12];
    float* out = (float*)d_out;

    // Workspace layout (floats):
    //   y2 : [0, 16777216)                 67.1 MB  (= seq; dead once back_last ran)
    //   y1 : [16777216, 33554432)          67.1 MB  (dead after conv2)
    //   xg : [16777216, 83886080)         268.4 MB  (overlays y1)
    //   flags: y2[0:8192)      32 KB  (padded: 1 flag per 128 B)  } overlay y2,
    //   xbuf : y2[8192:40960) 128 KB  (h-exchange, 2 slots/dir)   } after back_last
    float* ws = (float*)d_ws;
    float* y2 = ws;
    float* y1 = ws + (size_t)16777216;
    float* xg = ws + (size_t)16777216;
    int* flags = (int*)ws;
    unsigned int* xb = (unsigned int*)ws + 8192;

    // conv1: M=256, N=512, K=512
    wgemm_bias_relu<<<dim3(8, 4, BATCH), 256, 0, stream>>>(w1, x, b1, y1, HID, TT, CIN);
    // conv2: M=256, N=512, K=256
    wgemm_bias_relu<<<dim3(8, 4, BATCH), 256, 0, stream>>>(w2, y1, b2, y2, HID, TT, HID);
    // xg_f = seq @ w_ih_f^T + b_ih_f + b_hh_f : M=65536, N=1024, K=256
    gemm_abt_bias<<<dim3(16, 1024), 256, 0, stream>>>(y2, w_ih_f, b_ih_f, b_hh_f,
                                                      xg, BATCH * TT, GG, HID);
    // backward last step first (frees y2 region for the exchange buffers)
    lstm_back_last<<<BATCH, 256, 0, stream>>>(y2, w_ih_b, b_ih_b, b_hh_b, out);
    // zero the handshake flags (harness poisons ws each call)
    hipMemsetAsync(flags, 0, 32768, stream);
    // forward scan (writes out[:, 0:256))
    lstm_scan4<<<256, 1024, 0, stream>>>(xg, w_hh_f, out, xb, flags);
}

// Round 6
// 1569.537 us; speedup vs baseline: 3.8117x; 1.3669x over previous
//
#include <hip/hip_runtime.h>
#include <math.h>

// Sizes fixed by the problem
#define BATCH 128
#define TT 512      // time steps
#define CIN 512
#define HID 256
#define GG 1024     // 4*HID

typedef _Float16 half2_t __attribute__((ext_vector_type(2)));
typedef _Float16 half8_t __attribute__((ext_vector_type(8)));
typedef float f32x4_t __attribute__((ext_vector_type(4)));

__device__ __forceinline__ float sigf(float x) { return 1.f / (1.f + __expf(-x)); }
__device__ __forceinline__ float tanhf_(float x) {
    float a = fabsf(x);
    float e = __expf(-2.f * a);
    float r = (1.f - e) / (1.f + e);
    return copysignf(r, x);
}
__device__ __forceinline__ float fdot2_(half2_t a, half2_t b, float c) {
#if __has_builtin(__builtin_amdgcn_fdot2)
    return __builtin_amdgcn_fdot2(a, b, c, false);
#else
    return c + (float)a.x * (float)b.x + (float)a.y * (float)b.y;
#endif
}

// Tiny prep: cast w1/w2/w_ih_f to f16, sum LSTM biases. grid 1024x256.
__global__ void prep_cast(const float* __restrict__ w1, const float* __restrict__ w2,
                          const float* __restrict__ wih, const float* __restrict__ bih,
                          const float* __restrict__ bhh,
                          _Float16* __restrict__ w1h, _Float16* __restrict__ w2h,
                          _Float16* __restrict__ wihh, float* __restrict__ bsum)
{
    const int i = blockIdx.x * 256 + threadIdx.x;
    if (i < 131072) w1h[i] = (_Float16)w1[i];
    if (i < 65536)  w2h[i] = (_Float16)w2[i];
    if (i < 262144) wihh[i] = (_Float16)wih[i];
    if (i < 1024)   bsum[i] = bih[i] + bhh[i];
}

// x[b][c=512][t=512] fp32 -> xt[b][t][c] f16 (64x64 LDS tiles, coalesced both sides)
__global__ __launch_bounds__(256) void cast_transpose_x(
    const float* __restrict__ x, _Float16* __restrict__ xt)
{
    const int b = blockIdx.z, c0 = blockIdx.y * 64, t0 = blockIdx.x * 64;
    __shared__ float tl[64][68];
    const float* xb = x + (size_t)b * CIN * TT;
    const int tid = threadIdx.x;
    const int lt = (tid & 15) * 4, lc = tid >> 4;
    #pragma unroll
    for (int r = 0; r < 4; ++r) {
        const int c = lc + r * 16;
        float4 v = *(const float4*)(xb + (size_t)(c0 + c) * TT + t0 + lt);
        tl[c][lt] = v.x; tl[c][lt + 1] = v.y; tl[c][lt + 2] = v.z; tl[c][lt + 3] = v.w;
    }
    __syncthreads();
    const int trow = tid >> 2, coff = (tid & 3) * 16;
    _Float16 o[16];
    #pragma unroll
    for (int i = 0; i < 16; ++i) o[i] = (_Float16)tl[coff + i][trow];
    _Float16* dst = xt + (size_t)b * TT * CIN + (size_t)(t0 + trow) * CIN + c0 + coff;
    *(float4*)dst = *(float4*)&o[0];
    *(float4*)(dst + 8) = *(float4*)&o[8];
}

// C[M,N](f16) = op( A[M,K]f16 . B[N,K]f16^T + bias ), K%32==0, M%128==0, N%128==0.
// 128x128 tile, 256 thr = 4 waves of 64x64, v_mfma_f32_16x16x32_f16.
// Verified layouts (m89/m91/m120): A/B-frag idx=lane&15, k=quad*8+j (8 contig f16);
// D row=quad*4+reg (A's m), col=lane&15 (B's n). fp32 accumulate; LDS-bounce
// epilogue (2 passes of 64 rows) for coalesced f16 stores.
// BIASROW: bias indexed by output row (conv2: row=m), else by col.
template <int RELU, int BIASROW>
__global__ __launch_bounds__(256, 4) void mfma_nt(
    const _Float16* __restrict__ A, const _Float16* __restrict__ B,
    const float* __restrict__ bias, _Float16* __restrict__ C,
    int M, int N, int K, long sA, long sB, long sC)
{
    __shared__ __align__(16) char smem[34816];
    _Float16 (*As)[40] = (_Float16(*)[40])smem;
    _Float16 (*Bs)[40] = (_Float16(*)[40])(smem + 10240);
    float (*Ct)[132] = (float(*)[132])smem;   // 64 x 132 fp32 (union w/ stage)

    const int nb = blockIdx.z;
    A += (size_t)nb * sA; B += (size_t)nb * sB; C += (size_t)nb * sC;
    const int m0 = blockIdx.y * 128, n0 = blockIdx.x * 128;
    const int tid = threadIdx.x;
    const int wave = tid >> 6, lane = tid & 63;
    const int quad = lane >> 4, l15 = lane & 15;
    const int wm = (wave >> 1) * 64, wn = (wave & 1) * 64;
    const int srow = tid >> 1, sko = (tid & 1) * 16;   // staging map

    f32x4_t acc[4][4];
    const f32x4_t zz = {0.f, 0.f, 0.f, 0.f};
    #pragma unroll
    for (int i = 0; i < 4; ++i)
        #pragma unroll
        for (int j = 0; j < 4; ++j) acc[i][j] = zz;

    for (int k0 = 0; k0 < K; k0 += 32) {
        {   // stage A,B tiles: 128 rows x 32 k each; thread = 16 f16 per tile
            const float4* ga = (const float4*)(A + (size_t)(m0 + srow) * K + k0 + sko);
            float4 a0 = ga[0], a1 = ga[1];
            const float4* gb = (const float4*)(B + (size_t)(n0 + srow) * K + k0 + sko);
            float4 b0 = gb[0], b1 = gb[1];
            *(float4*)&As[srow][sko] = a0; *(float4*)&As[srow][sko + 8] = a1;
            *(float4*)&Bs[srow][sko] = b0; *(float4*)&Bs[srow][sko + 8] = b1;
        }
        __syncthreads();
        half8_t af[4], bf[4];
        #pragma unroll
        for (int i = 0; i < 4; ++i) af[i] = *(const half8_t*)&As[wm + i * 16 + l15][quad * 8];
        #pragma unroll
        for (int j = 0; j < 4; ++j) bf[j] = *(const half8_t*)&Bs[wn + j * 16 + l15][quad * 8];
        #pragma unroll
        for (int i = 0; i < 4; ++i)
            #pragma unroll
            for (int j = 0; j < 4; ++j)
                acc[i][j] = __builtin_amdgcn_mfma_f32_16x16x32_f16(af[i], bf[j], acc[i][j], 0, 0, 0);
        __syncthreads();
    }

    // epilogue: bounce 64-row halves through LDS (fp32), bias+relu+cvt, coalesced store
    const int trow = tid >> 2, coff = (tid & 3) * 32;
    float bcol[32];
    if (!BIASROW) {
        #pragma unroll
        for (int i = 0; i < 8; ++i)
            *(float4*)&bcol[i * 4] = *(const float4*)&bias[n0 + coff + i * 4];
    }
    #pragma unroll
    for (int p = 0; p < 2; ++p) {
        if (p) __syncthreads();
        if ((wave >> 1) == p) {
            #pragma unroll
            for (int mi = 0; mi < 4; ++mi)
                #pragma unroll
                for (int ni = 0; ni < 4; ++ni)
                    #pragma unroll
                    for (int r = 0; r < 4; ++r)
                        Ct[mi * 16 + quad * 4 + r][wn + ni * 16 + l15] = acc[mi][ni][r];
        }
        __syncthreads();
        float brow = 0.f;
        if (BIASROW) brow = bias[m0 + p * 64 + trow];
        float vv[32];
        #pragma unroll
        for (int i = 0; i < 8; ++i) *(float4*)&vv[i * 4] = *(float4*)&Ct[trow][coff + i * 4];
        _Float16 o[32];
        #pragma unroll
        for (int i = 0; i < 32; ++i) {
            float v = vv[i] + (BIASROW ? brow : bcol[i]);
            if (RELU) v = fmaxf(v, 0.f);
            o[i] = (_Float16)v;
        }
        _Float16* dst = C + (size_t)(m0 + p * 64 + trow) * N + n0 + coff;
        #pragma unroll
        for (int i = 0; i < 4; ++i) *(float4*)(dst + i * 8) = *(float4*)&o[i * 8];
    }
}

// Forward LSTM scan v4 (round-5 proven): 2 blocks/batch, register-resident f16
// weights (FULL unroll -> static w[] indices), wave-uniform broadcast LDS
// h-reads (0 conflicts), single-wave finisher + MALL exchange.
// Round 6 change: xg is now f16 (loads cast to fp32).
__global__ __launch_bounds__(1024, 4) void lstm_scan4(
    const _Float16* __restrict__ xg, const float* __restrict__ whh,
    float* __restrict__ out, unsigned int* __restrict__ xb,
    int* __restrict__ flags)
{
    const int tid = threadIdx.x;
    const int bid = blockIdx.x;
    const int is_hi = (bid >= 128) ? 1 : 0;
    const int g = is_hi ? bid - 128 : bid;
    const int partner = is_hi ? bid - 128 : bid + 128;
    const int half = tid >> 9;
    const int rw = tid & 511;
    const int q = rw >> 7;
    const int u = rw & 127;
    const int row = q * 256 + is_hi * 128 + u;

    __shared__ __align__(16) unsigned int hsh[128];
    __shared__ float psh[1024];

    half2_t w[64];
    {
        const float4* wp = (const float4*)(whh + (size_t)row * 256 + half * 128);
        #pragma unroll
        for (int k = 0; k < 32; ++k) {
            float4 a = wp[k];
            w[2 * k + 0] = half2_t{(_Float16)a.x, (_Float16)a.y};
            w[2 * k + 1] = half2_t{(_Float16)a.z, (_Float16)a.w};
        }
    }
    if (tid < 128) hsh[tid] = 0u;
    const _Float16* xgb = xg + (size_t)g * TT * GG;
    float xnext = (half == 0) ? (float)xgb[row] : 0.f;
    float c0 = 0.f, c1 = 0.f, hk0 = 0.f, hk1 = 0.f;
    __syncthreads();

    for (int t = 0; t < TT; ++t) {
        const float xv = xnext;
        if (half == 0 && t < TT - 1) xnext = (float)xgb[(size_t)(t + 1) * GG + row];
        float a0 = 0.f, a1 = 0.f, a2 = 0.f, a3 = 0.f;
        const float4* hp = (const float4*)hsh + (half << 4);
        #pragma unroll
        for (int kk = 0; kk < 16; ++kk) {
            const float4 hv = hp[kk];   // wave-uniform address -> broadcast
            a0 = fdot2_(w[4 * kk + 0], __builtin_bit_cast(half2_t, hv.x), a0);
            a1 = fdot2_(w[4 * kk + 1], __builtin_bit_cast(half2_t, hv.y), a1);
            a2 = fdot2_(w[4 * kk + 2], __builtin_bit_cast(half2_t, hv.z), a2);
            a3 = fdot2_(w[4 * kk + 3], __builtin_bit_cast(half2_t, hv.w), a3);
        }
        psh[tid] = (a0 + a1) + (a2 + a3) + xv;
        __syncthreads();               // B1
        if (tid < 64) {
            const int l = tid;
            const float2* pl = (const float2*)psh;
            const float2* ph = (const float2*)(psh + 512);
            const float2 iv = pl[l],       iw = ph[l];
            const float2 fv = pl[64 + l],  fw = ph[64 + l];
            const float2 gv = pl[128 + l], gw = ph[128 + l];
            const float2 ov = pl[192 + l], ow = ph[192 + l];
            const float i0 = sigf(iv.x + iw.x), i1 = sigf(iv.y + iw.y);
            const float f0 = sigf(fv.x + fw.x), f1 = sigf(fv.y + fw.y);
            const float g0 = tanhf_(gv.x + gw.x), g1 = tanhf_(gv.y + gw.y);
            const float o0 = sigf(ov.x + ow.x), o1 = sigf(ov.y + ow.y);
            c0 = f0 * c0 + i0 * g0;  hk0 = o0 * tanhf_(c0);
            c1 = f1 * c1 + i1 * g1;  hk1 = o1 * tanhf_(c1);
            const unsigned int hv =
                (unsigned int)__builtin_bit_cast(unsigned short, (_Float16)hk0) |
                ((unsigned int)__builtin_bit_cast(unsigned short, (_Float16)hk1) << 16);
            hsh[is_hi * 64 + l] = hv;
            if (t < TT - 1) {
                unsigned int* dst =
                    xb + (((size_t)g * 2 + (t & 1)) * 2 + is_hi) * 64;
                __hip_atomic_store(&dst[l], hv, __ATOMIC_RELAXED,
                                   __HIP_MEMORY_SCOPE_AGENT);
                asm volatile("s_waitcnt vmcnt(0)" ::: "memory");
                if (l == 0) {
                    __hip_atomic_store(&flags[bid * 32], t + 1,
                                       __ATOMIC_RELAXED, __HIP_MEMORY_SCOPE_AGENT);
                    while (__hip_atomic_load(&flags[partner * 32],
                                             __ATOMIC_RELAXED,
                                             __HIP_MEMORY_SCOPE_AGENT) < t + 1)
                        __builtin_amdgcn_s_sleep(1);
                }
                asm volatile("" ::: "memory");
                const unsigned int* src =
                    xb + (((size_t)g * 2 + (t & 1)) * 2 + (1 - is_hi)) * 64;
                hsh[(1 - is_hi) * 64 + l] =
                    __hip_atomic_load(&src[l], __ATOMIC_RELAXED,
                                      __HIP_MEMORY_SCOPE_AGENT);
            }
        }
        __syncthreads();               // B2
    }
    if (tid < 64) {
        out[(size_t)g * 512 + is_hi * 128 + 2 * tid + 0] = hk0;
        out[(size_t)g * 512 + is_hi * 128 + 2 * tid + 1] = hk1;
    }
}

// Backward-direction LSTM last step (h=c=0): needs only seq[:,T-1,:].
__global__ __launch_bounds__(256) void lstm_back_last(
    const _Float16* __restrict__ y2h, const float* __restrict__ wih,
    const float* __restrict__ bih, const float* __restrict__ bhh,
    float* __restrict__ out)
{
    const int b = blockIdx.x;
    const int t = threadIdx.x;
    __shared__ float s[256];
    s[t] = (float)y2h[(size_t)b * (HID * TT) + (TT - 1) * HID + t];
    __syncthreads();
    float acc[4];
    #pragma unroll
    for (int q = 0; q < 4; ++q) acc[q] = bih[t + q * 256] + bhh[t + q * 256];
    #pragma unroll
    for (int q = 0; q < 4; ++q) {
        const float* w = wih + (size_t)(t + q * 256) * 256;
        float a = acc[q];
        for (int k = 0; k < 256; k += 4) {
            const float4 w4 = *(const float4*)&w[k];
            const float4 h4 = *(const float4*)&s[k];
            a += w4.x * h4.x; a += w4.y * h4.y;
            a += w4.z * h4.z; a += w4.w * h4.w;
        }
        acc[q] = a;
    }
    const float i = sigf(acc[0]);
    const float g = tanhf_(acc[2]), o = sigf(acc[3]);
    const float c = i * g;
    const float h = o * tanhf_(c);
    out[(size_t)b * 512 + 256 + t] = h;
}

extern "C" void kernel_launch(void* const* d_in, const int* in_sizes, int n_in,
                              void* d_out, int out_size, void* d_ws, size_t ws_size,
                              hipStream_t stream) {
    const float* x      = (const float*)d_in[0];
    const float* w1     = (const float*)d_in[1];
    const float* b1     = (const float*)d_in[2];
    const float* w2     = (const float*)d_in[3];
    const float* b2     = (const float*)d_in[4];
    const float* w_ih_f = (const float*)d_in[5];
    const float* w_hh_f = (const float*)d_in[6];
    const float* b_ih_f = (const float*)d_in[7];
    const float* b_hh_f = (const float*)d_in[8];
    const float* w_ih_b = (const float*)d_in[9];
    // d_in[10] = w_hh_b: provably unused (only first reversed step reaches output)
    const float* b_ih_b = (const float*)d_in[11];
    const float* b_hh_b = (const float*)d_in[12];
    float* out = (float*)d_out;

    // Workspace layout (bytes):
    //   xgh  f16 [65536][1024] :         0 .. 134217728
    //   xt   f16 [128][512][512]: 134217728 .. 201326592
    //   y1t  f16 [128][512][256]: 201326592 .. 234881024   (= y1^T per batch)
    //   y2h  f16 [128][256][512]: 234881024 .. 268435456   (canonical = seq flat)
    //   w1h  f16 131072        : 268435456 .. 268697600
    //   w2h  f16 65536         : 268697600 .. 268828672
    //   wihh f16 262144        : 268828672 .. 269352960
    //   bsum f32 1024          : 269352960 .. 269357056
    //   flags i32 (128B-padded): 269357056 .. 269389824
    //   xb   u32 32768         : 269389824 .. 269520896    (~257 MB total)
    char* ws = (char*)d_ws;
    _Float16* xgh  = (_Float16*)(ws);
    _Float16* xt   = (_Float16*)(ws + 134217728);
    _Float16* y1t  = (_Float16*)(ws + 201326592);
    _Float16* y2h  = (_Float16*)(ws + 234881024);
    _Float16* w1h  = (_Float16*)(ws + 268435456);
    _Float16* w2h  = (_Float16*)(ws + 268697600);
    _Float16* wihh = (_Float16*)(ws + 268828672);
    float*    bsum = (float*)   (ws + 269352960);
    int*      flags= (int*)     (ws + 269357056);
    unsigned int* xb = (unsigned int*)(ws + 269389824);

    hipMemsetAsync(flags, 0, 32768, stream);
    prep_cast<<<1024, 256, 0, stream>>>(w1, w2, w_ih_f, b_ih_f, b_hh_f,
                                        w1h, w2h, wihh, bsum);
    cast_transpose_x<<<dim3(8, 8, BATCH), 256, 0, stream>>>(x, xt);
    // conv1: y1t[b][t][m1] = relu( xt[b][t][:] . w1h[m1][:] + b1[m1] )   (bias on col)
    mfma_nt<1, 0><<<dim3(2, 4, BATCH), 256, 0, stream>>>(
        xt, w1h, b1, y1t, 512, 256, 512, 512L * 512, 0, 512L * 256);
    // conv2: y2h[b][m2][t] = relu( w2h[m2][:] . y1t[b][t][:] + b2[m2] )  (bias on row)
    mfma_nt<1, 1><<<dim3(4, 2, BATCH), 256, 0, stream>>>(
        w2h, y1t, b2, y2h, 256, 512, 256, 0, 512L * 256, 256L * 512);
    // xg: xgh[r][g] = y2h-flat[r][:] . wihh[g][:] + bsum[g]              (bias on col)
    mfma_nt<0, 0><<<dim3(8, 512, 1), 256, 0, stream>>>(
        y2h, wihh, bsum, xgh, 65536, 1024, 256, 0, 0, 0);
    // backward last step (writes out[:, 256:512))
    lstm_back_last<<<BATCH, 256, 0, stream>>>(y2h, w_ih_b, b_ih_b, b_hh_b, out);
    // forward scan (writes out[:, 0:256))
    lstm_scan4<<<256, 1024, 0, stream>>>(xgh, w_hh_f, out, xb, flags);
}

// Round 7
// 1285.961 us; speedup vs baseline: 4.6522x; 1.2205x over previous
//
#include <hip/hip_runtime.h>
#include <math.h>

// Sizes fixed by the problem
#define BATCH 128
#define TT 512      // time steps
#define CIN 512
#define HID 256
#define GG 1024     // 4*HID

typedef _Float16 half2_t __attribute__((ext_vector_type(2)));
typedef _Float16 half8_t __attribute__((ext_vector_type(8)));
typedef float f32x4_t __attribute__((ext_vector_type(4)));

__device__ __forceinline__ float sigf(float x) { return 1.f / (1.f + __expf(-x)); }
__device__ __forceinline__ float tanhf_(float x) {
    float a = fabsf(x);
    float e = __expf(-2.f * a);
    float r = (1.f - e) / (1.f + e);
    return copysignf(r, x);
}
__device__ __forceinline__ float fdot2_(half2_t a, half2_t b, float c) {
#if __has_builtin(__builtin_amdgcn_fdot2)
    return __builtin_amdgcn_fdot2(a, b, c, false);
#else
    return c + (float)a.x * (float)b.x + (float)a.y * (float)b.y;
#endif
}

// Tiny prep: cast w1/w2/w_ih_f to f16, sum LSTM biases. grid 1024x256.
__global__ void prep_cast(const float* __restrict__ w1, const float* __restrict__ w2,
                          const float* __restrict__ wih, const float* __restrict__ bih,
                          const float* __restrict__ bhh,
                          _Float16* __restrict__ w1h, _Float16* __restrict__ w2h,
                          _Float16* __restrict__ wihh, float* __restrict__ bsum)
{
    const int i = blockIdx.x * 256 + threadIdx.x;
    if (i < 131072) w1h[i] = (_Float16)w1[i];
    if (i < 65536)  w2h[i] = (_Float16)w2[i];
    if (i < 262144) wihh[i] = (_Float16)wih[i];
    if (i < 1024)   bsum[i] = bih[i] + bhh[i];
}

// x[b][c=512][t=512] fp32 -> xt[b][t][c] f16 (64x64 LDS tiles, coalesced both sides)
__global__ __launch_bounds__(256) void cast_transpose_x(
    const float* __restrict__ x, _Float16* __restrict__ xt)
{
    const int b = blockIdx.z, c0 = blockIdx.y * 64, t0 = blockIdx.x * 64;
    __shared__ float tl[64][68];
    const float* xb = x + (size_t)b * CIN * TT;
    const int tid = threadIdx.x;
    const int lt = (tid & 15) * 4, lc = tid >> 4;
    #pragma unroll
    for (int r = 0; r < 4; ++r) {
        const int c = lc + r * 16;
        float4 v = *(const float4*)(xb + (size_t)(c0 + c) * TT + t0 + lt);
        tl[c][lt] = v.x; tl[c][lt + 1] = v.y; tl[c][lt + 2] = v.z; tl[c][lt + 3] = v.w;
    }
    __syncthreads();
    const int trow = tid >> 2, coff = (tid & 3) * 16;
    _Float16 o[16];
    #pragma unroll
    for (int i = 0; i < 16; ++i) o[i] = (_Float16)tl[coff + i][trow];
    _Float16* dst = xt + (size_t)b * TT * CIN + (size_t)(t0 + trow) * CIN + c0 + coff;
    *(float4*)dst = *(float4*)&o[0];
    *(float4*)(dst + 8) = *(float4*)&o[8];
}

// C[M,N](f16) = op( A[M,K]f16 . B[N,K]f16^T + bias ), K%32==0, M%128==0, N%128==0.
// 128x128 tile, 256 thr = 4 waves of 64x64, v_mfma_f32_16x16x32_f16.
// A/B-frag idx=lane&15, k=quad*8+j; D row=quad*4+reg, col=lane&15 (verified).
template <int RELU, int BIASROW>
__global__ __launch_bounds__(256, 4) void mfma_nt(
    const _Float16* __restrict__ A, const _Float16* __restrict__ B,
    const float* __restrict__ bias, _Float16* __restrict__ C,
    int M, int N, int K, long sA, long sB, long sC)
{
    __shared__ __align__(16) char smem[34816];
    _Float16 (*As)[40] = (_Float16(*)[40])smem;
    _Float16 (*Bs)[40] = (_Float16(*)[40])(smem + 10240);
    float (*Ct)[132] = (float(*)[132])smem;   // 64 x 132 fp32 (union w/ stage)

    const int nb = blockIdx.z;
    A += (size_t)nb * sA; B += (size_t)nb * sB; C += (size_t)nb * sC;
    const int m0 = blockIdx.y * 128, n0 = blockIdx.x * 128;
    const int tid = threadIdx.x;
    const int wave = tid >> 6, lane = tid & 63;
    const int quad = lane >> 4, l15 = lane & 15;
    const int wm = (wave >> 1) * 64, wn = (wave & 1) * 64;
    const int srow = tid >> 1, sko = (tid & 1) * 16;   // staging map

    f32x4_t acc[4][4];
    const f32x4_t zz = {0.f, 0.f, 0.f, 0.f};
    #pragma unroll
    for (int i = 0; i < 4; ++i)
        #pragma unroll
        for (int j = 0; j < 4; ++j) acc[i][j] = zz;

    for (int k0 = 0; k0 < K; k0 += 32) {
        {   // stage A,B tiles: 128 rows x 32 k each; thread = 16 f16 per tile
            const float4* ga = (const float4*)(A + (size_t)(m0 + srow) * K + k0 + sko);
            float4 a0 = ga[0], a1 = ga[1];
            const float4* gb = (const float4*)(B + (size_t)(n0 + srow) * K + k0 + sko);
            float4 b0 = gb[0], b1 = gb[1];
            *(float4*)&As[srow][sko] = a0; *(float4*)&As[srow][sko + 8] = a1;
            *(float4*)&Bs[srow][sko] = b0; *(float4*)&Bs[srow][sko + 8] = b1;
        }
        __syncthreads();
        half8_t af[4], bf[4];
        #pragma unroll
        for (int i = 0; i < 4; ++i) af[i] = *(const half8_t*)&As[wm + i * 16 + l15][quad * 8];
        #pragma unroll
        for (int j = 0; j < 4; ++j) bf[j] = *(const half8_t*)&Bs[wn + j * 16 + l15][quad * 8];
        #pragma unroll
        for (int i = 0; i < 4; ++i)
            #pragma unroll
            for (int j = 0; j < 4; ++j)
                acc[i][j] = __builtin_amdgcn_mfma_f32_16x16x32_f16(af[i], bf[j], acc[i][j], 0, 0, 0);
        __syncthreads();
    }

    // epilogue: bounce 64-row halves through LDS (fp32), bias+relu+cvt, coalesced store
    const int trow = tid >> 2, coff = (tid & 3) * 32;
    float bcol[32];
    if (!BIASROW) {
        #pragma unroll
        for (int i = 0; i < 8; ++i)
            *(float4*)&bcol[i * 4] = *(const float4*)&bias[n0 + coff + i * 4];
    }
    #pragma unroll
    for (int p = 0; p < 2; ++p) {
        if (p) __syncthreads();
        if ((wave >> 1) == p) {
            #pragma unroll
            for (int mi = 0; mi < 4; ++mi)
                #pragma unroll
                for (int ni = 0; ni < 4; ++ni)
                    #pragma unroll
                    for (int r = 0; r < 4; ++r)
                        Ct[mi * 16 + quad * 4 + r][wn + ni * 16 + l15] = acc[mi][ni][r];
        }
        __syncthreads();
        float brow = 0.f;
        if (BIASROW) brow = bias[m0 + p * 64 + trow];
        float vv[32];
        #pragma unroll
        for (int i = 0; i < 8; ++i) *(float4*)&vv[i * 4] = *(float4*)&Ct[trow][coff + i * 4];
        _Float16 o[32];
        #pragma unroll
        for (int i = 0; i < 32; ++i) {
            float v = vv[i] + (BIASROW ? brow : bcol[i]);
            if (RELU) v = fmaxf(v, 0.f);
            o[i] = (_Float16)v;
        }
        _Float16* dst = C + (size_t)(m0 + p * 64 + trow) * N + n0 + coff;
        #pragma unroll
        for (int i = 0; i < 4; ++i) *(float4*)(dst + i * 8) = *(float4*)&o[i * 8];
    }
}

// Forward LSTM scan v5: quarter-K thread map + self-tagged MALL exchange.
//   block bid < 128:  batch bid,      units [0,128)   ("lo")
//   block bid >= 128: batch bid-128,  units [128,256) ("hi")
// Thread = (K-quarter q4 = tid>>8, s = tid&255). Owns rows (s, s+256) of the
// block's 512 gate rows over k in [64*q4, 64*q4+64): 64 half2 weight VGPRs,
// statically indexed (full unroll -> no spill; round-4 lesson).
// q4 is wave-uniform -> all dot-phase ds_read_b128 are broadcast (0 conflicts)
// and per-CU read count halves vs v4 (128 vs 256 per step).
// Exchange: 64 u64 words/side, each u32 = (t+1)<<16 | h_f16 (self-tagged).
// Publish-then-poll on the data itself: no vmcnt(0) stall, no separate flag,
// one poll RT instead of three dependent MALL RTs. Tag equality is ABA-safe
// (monotone tags; 0xAA poison = tag 43690 never matches t+1 in [1,511]).
__global__ __launch_bounds__(1024, 4) void lstm_scan5(
    const _Float16* __restrict__ xg, const float* __restrict__ whh,
    float* __restrict__ out, unsigned long long* __restrict__ xb)
{
    const int tid = threadIdx.x;
    const int bid = blockIdx.x;
    const int is_hi = (bid >= 128) ? 1 : 0;
    const int g = is_hi ? bid - 128 : bid;
    const int q4 = tid >> 8;           // K-quarter (wave-uniform)
    const int s = tid & 255;
    const int u = s & 127;
    const int rowA = (s >> 7) * 256 + is_hi * 128 + u;  // gate 0/1 row
    const int rowB = rowA + 512;                        // gate 2/3 row

    __shared__ __align__(16) unsigned int hsh[128];  // h: 256 f16 (lo|hi)
    __shared__ float psh[2048];                      // [quarter][512 rows]

    half2_t wA[32], wB[32];
    {
        const float4* pa = (const float4*)(whh + (size_t)rowA * 256 + q4 * 64);
        const float4* pb = (const float4*)(whh + (size_t)rowB * 256 + q4 * 64);
        #pragma unroll
        for (int k = 0; k < 16; ++k) {
            float4 a = pa[k], b = pb[k];
            wA[2 * k + 0] = half2_t{(_Float16)a.x, (_Float16)a.y};
            wA[2 * k + 1] = half2_t{(_Float16)a.z, (_Float16)a.w};
            wB[2 * k + 0] = half2_t{(_Float16)b.x, (_Float16)b.y};
            wB[2 * k + 1] = half2_t{(_Float16)b.z, (_Float16)b.w};
        }
    }
    if (tid < 128) hsh[tid] = 0u;
    const _Float16* xgb = xg + (size_t)g * TT * GG;
    float xA = 0.f, xB = 0.f;
    if (q4 == 0) { xA = (float)xgb[rowA]; xB = (float)xgb[rowB]; }
    float c0 = 0.f, c1 = 0.f, hk0 = 0.f, hk1 = 0.f;   // wave-0 lane state
    __syncthreads();

    for (int t = 0; t < TT; ++t) {
        const float vA = xA, vB = xB;
        if (q4 == 0 && t < TT - 1) {   // prefetch next xg behind the dot loop
            xA = (float)xgb[(size_t)(t + 1) * GG + rowA];
            xB = (float)xgb[(size_t)(t + 1) * GG + rowB];
        }
        float aA0 = 0.f, aA1 = 0.f, aB0 = 0.f, aB1 = 0.f;
        const float4* hp = (const float4*)hsh + q4 * 8;
        #pragma unroll
        for (int kk = 0; kk < 8; ++kk) {
            const float4 hv = hp[kk];   // wave-uniform address -> broadcast
            const half2_t h0 = __builtin_bit_cast(half2_t, hv.x);
            const half2_t h1 = __builtin_bit_cast(half2_t, hv.y);
            const half2_t h2 = __builtin_bit_cast(half2_t, hv.z);
            const half2_t h3 = __builtin_bit_cast(half2_t, hv.w);
            aA0 = fdot2_(wA[4 * kk + 0], h0, aA0);
            aA1 = fdot2_(wA[4 * kk + 1], h1, aA1);
            aA0 = fdot2_(wA[4 * kk + 2], h2, aA0);
            aA1 = fdot2_(wA[4 * kk + 3], h3, aA1);
            aB0 = fdot2_(wB[4 * kk + 0], h0, aB0);
            aB1 = fdot2_(wB[4 * kk + 1], h1, aB1);
            aB0 = fdot2_(wB[4 * kk + 2], h2, aB0);
            aB1 = fdot2_(wB[4 * kk + 3], h3, aB1);
        }
        psh[q4 * 512 + s]       = aA0 + aA1 + vA;
        psh[q4 * 512 + 256 + s] = aB0 + aB1 + vB;
        __syncthreads();               // B1: partials staged; h reads done
        if (tid < 64) {                // wave 0 finishes units 2l, 2l+1
            const int l = tid;
            float2 gate[4];
            #pragma unroll
            for (int gg = 0; gg < 4; ++gg) {
                float2 sum = {0.f, 0.f};
                #pragma unroll
                for (int qq = 0; qq < 4; ++qq) {
                    const float2 v = *(const float2*)&psh[qq * 512 + gg * 128 + 2 * l];
                    sum.x += v.x; sum.y += v.y;
                }
                gate[gg] = sum;
            }
            const float i0 = sigf(gate[0].x), i1 = sigf(gate[0].y);
            const float f0 = sigf(gate[1].x), f1 = sigf(gate[1].y);
            const float g0 = tanhf_(gate[2].x), g1 = tanhf_(gate[2].y);
            const float o0 = sigf(gate[3].x), o1 = sigf(gate[3].y);
            c0 = f0 * c0 + i0 * g0;  hk0 = o0 * tanhf_(c0);
            c1 = f1 * c1 + i1 * g1;  hk1 = o1 * tanhf_(c1);
            const unsigned int u0 =
                (unsigned int)__builtin_bit_cast(unsigned short, (_Float16)hk0);
            const unsigned int u1 =
                (unsigned int)__builtin_bit_cast(unsigned short, (_Float16)hk1);
            hsh[is_hi * 64 + l] = u0 | (u1 << 16);   // own half into LDS
            if (t < TT - 1) {
                const unsigned int tg = (unsigned int)(t + 1) << 16;
                const unsigned long long pk =
                    ((unsigned long long)(tg | u1) << 32) | (unsigned long long)(tg | u0);
                __hip_atomic_store(&xb[((size_t)g * 2 + is_hi) * 64 + l], pk,
                                   __ATOMIC_RELAXED, __HIP_MEMORY_SCOPE_AGENT);
                asm volatile("" ::: "memory");
                unsigned long long v;
                const unsigned long long* src = &xb[((size_t)g * 2 + (1 - is_hi)) * 64 + l];
                for (;;) {
                    v = __hip_atomic_load(src, __ATOMIC_RELAXED,
                                          __HIP_MEMORY_SCOPE_AGENT);
                    if ((((v >> 16) & 0xFFFFu) == (unsigned)(t + 1)) &&
                        ((unsigned)(v >> 48) == (unsigned)(t + 1))) break;
                    __builtin_amdgcn_s_sleep(1);
                }
                hsh[(1 - is_hi) * 64 + l] =
                    (unsigned int)(v & 0xFFFFu) |
                    ((unsigned int)((v >> 32) & 0xFFFFu) << 16);
            }
        }
        __syncthreads();               // B2: h (own + partner) visible to all
    }
    if (tid < 64) {
        out[(size_t)g * 512 + is_hi * 128 + 2 * tid + 0] = hk0;
        out[(size_t)g * 512 + is_hi * 128 + 2 * tid + 1] = hk1;
    }
}

// Backward-direction LSTM last step (h=c=0): needs only seq[:,T-1,:].
__global__ __launch_bounds__(256) void lstm_back_last(
    const _Float16* __restrict__ y2h, const float* __restrict__ wih,
    const float* __restrict__ bih, const float* __restrict__ bhh,
    float* __restrict__ out)
{
    const int b = blockIdx.x;
    const int t = threadIdx.x;
    __shared__ float s[256];
    s[t] = (float)y2h[(size_t)b * (HID * TT) + (TT - 1) * HID + t];
    __syncthreads();
    float acc[4];
    #pragma unroll
    for (int q = 0; q < 4; ++q) acc[q] = bih[t + q * 256] + bhh[t + q * 256];
    #pragma unroll
    for (int q = 0; q < 4; ++q) {
        const float* w = wih + (size_t)(t + q * 256) * 256;
        float a = acc[q];
        for (int k = 0; k < 256; k += 4) {
            const float4 w4 = *(const float4*)&w[k];
            const float4 h4 = *(const float4*)&s[k];
            a += w4.x * h4.x; a += w4.y * h4.y;
            a += w4.z * h4.z; a += w4.w * h4.w;
        }
        acc[q] = a;
    }
    const float i = sigf(acc[0]);
    const float g = tanhf_(acc[2]), o = sigf(acc[3]);
    const float c = i * g;           // c_prev = 0, forget path vanishes
    const float h = o * tanhf_(c);
    out[(size_t)b * 512 + 256 + t] = h;
}

extern "C" void kernel_launch(void* const* d_in, const int* in_sizes, int n_in,
                              void* d_out, int out_size, void* d_ws, size_t ws_size,
                              hipStream_t stream) {
    const float* x      = (const float*)d_in[0];
    const float* w1     = (const float*)d_in[1];
    const float* b1     = (const float*)d_in[2];
    const float* w2     = (const float*)d_in[3];
    const float* b2     = (const float*)d_in[4];
    const float* w_ih_f = (const float*)d_in[5];
    const float* w_hh_f = (const float*)d_in[6];
    const float* b_ih_f = (const float*)d_in[7];
    const float* b_hh_f = (const float*)d_in[8];
    const float* w_ih_b = (const float*)d_in[9];
    // d_in[10] = w_hh_b: provably unused (only first reversed step reaches output)
    const float* b_ih_b = (const float*)d_in[11];
    const float* b_hh_b = (const float*)d_in[12];
    float* out = (float*)d_out;

    // Workspace layout (bytes):
    //   xgh  f16 [65536][1024] :         0 .. 134217728
    //   xt   f16 [128][512][512]: 134217728 .. 201326592
    //   y1t  f16 [128][512][256]: 201326592 .. 234881024   (= y1^T per batch)
    //   y2h  f16 [128][256][512]: 234881024 .. 268435456   (canonical = seq flat)
    //   w1h  f16 131072        : 268435456 .. 268697600
    //   w2h  f16 65536         : 268697600 .. 268828672
    //   wihh f16 262144        : 268828672 .. 269352960
    //   bsum f32 1024          : 269352960 .. 269357056
    //   xb   u64 16384         : 269357056 .. 269488128   (tagged h exchange)
    char* ws = (char*)d_ws;
    _Float16* xgh  = (_Float16*)(ws);
    _Float16* xt   = (_Float16*)(ws + 134217728);
    _Float16* y1t  = (_Float16*)(ws + 201326592);
    _Float16* y2h  = (_Float16*)(ws + 234881024);
    _Float16* w1h  = (_Float16*)(ws + 268435456);
    _Float16* w2h  = (_Float16*)(ws + 268697600);
    _Float16* wihh = (_Float16*)(ws + 268828672);
    float*    bsum = (float*)   (ws + 269352960);
    unsigned long long* xb = (unsigned long long*)(ws + 269357056);

    prep_cast<<<1024, 256, 0, stream>>>(w1, w2, w_ih_f, b_ih_f, b_hh_f,
                                        w1h, w2h, wihh, bsum);
    cast_transpose_x<<<dim3(8, 8, BATCH), 256, 0, stream>>>(x, xt);
    // conv1: y1t[b][t][m1] = relu( xt[b][t][:] . w1h[m1][:] + b1[m1] )   (bias on col)
    mfma_nt<1, 0><<<dim3(2, 4, BATCH), 256, 0, stream>>>(
        xt, w1h, b1, y1t, 512, 256, 512, 512L * 512, 0, 512L * 256);
    // conv2: y2h[b][m2][t] = relu( w2h[m2][:] . y1t[b][t][:] + b2[m2] )  (bias on row)
    mfma_nt<1, 1><<<dim3(4, 2, BATCH), 256, 0, stream>>>(
        w2h, y1t, b2, y2h, 256, 512, 256, 0, 512L * 256, 256L * 512);
    // xg: xgh[r][g] = y2h-flat[r][:] . wihh[g][:] + bsum[g]              (bias on col)
    mfma_nt<0, 0><<<dim3(8, 512, 1), 256, 0, stream>>>(
        y2h, wihh, bsum, xgh, 65536, 1024, 256, 0, 0, 0);
    // backward last step (writes out[:, 256:512))
    lstm_back_last<<<BATCH, 256, 0, stream>>>(y2h, w_ih_b, b_ih_b, b_hh_b, out);
    // forward scan (writes out[:, 0:256))
    lstm_scan5<<<256, 1024, 0, stream>>>(xgh, w_hh_f, out, xb);
}